// Round 3
// baseline (445.168 us; speedup 1.0000x reference)
//
#include <hip/hip_runtime.h>
#include <math.h>

#define GN 16
#define NCELL 4096
#define CAP 64

// ws layout (ints): hist[4096] @ 0, bucket[4096*CAP] @ 4096

__device__ __forceinline__ int cell_of(float x0, float x1, float x2) {
    int ix = (int)(x0 / 0.1875f + 8.0f); ix = ix < 0 ? 0 : (ix > 15 ? 15 : ix);
    int iy = (int)(x1 / 0.1875f + 8.0f); iy = iy < 0 ? 0 : (iy > 15 ? 15 : iy);
    int iz = (int)(x2 / 0.1875f + 8.0f); iz = iz < 0 ? 0 : (iz > 15 ? 15 : iz);
    return (ix * GN + iy) * GN + iz;
}

// emb layout: [v0,v1,v2, sin(2^0 v*), cos(2^0 v*), sin(2^1 v*), ...]
__device__ __forceinline__ float emb_val(int m, float v0, float v1, float v2) {
    if (m == 0) return v0;
    if (m == 1) return v1;
    if (m == 2) return v2;
    int t = m - 3, j = t / 6, rem = t - j * 6, comp = rem % 3;
    float v = (comp == 0) ? v0 : ((comp == 1) ? v1 : v2);
    float s = ldexpf(v, j);
    return (rem < 3) ? sinf(s) : cosf(s);
}

__global__ void k_zero(int* __restrict__ hist) {
    int t = blockIdx.x * blockDim.x + threadIdx.x;
    if (t < NCELL) hist[t] = 0;
}

__global__ void k_bin(const float* __restrict__ xg, float* __restrict__ out,
                      int* __restrict__ hist, int* __restrict__ bucket, int P) {
    int p = blockIdx.x * blockDim.x + threadIdx.x;
    if (p >= P) return;
    float x0 = xg[p*3+0], x1 = xg[p*3+1], x2 = xg[p*3+2];
    bool mask = (fabsf(x0) < 1.5f) && (fabsf(x1) < 1.5f) && (fabsf(x2) < 1.5f);
    if (mask) {
        int c = cell_of(x0, x1, x2);
        int slot = atomicAdd(&hist[c], 1);
        if (slot < CAP) bucket[c*CAP + slot] = p;
    } else {
        out[p*3+0] = 0.0f; out[p*3+1] = 0.0f; out[p*3+2] = 0.0f;
        out[(size_t)P*3 + p] = 0.0f;
    }
}

// one 64-thread (1-wave) block per cell; 8 lanes per point, lane k owns outputs 4k..4k+3
__global__ __launch_bounds__(64) void k_fwd(
    const float* __restrict__ xg, const float* __restrict__ dg,
    const float* __restrict__ l1w, const float* __restrict__ l1b,
    const float* __restrict__ l2w, const float* __restrict__ l2b,
    const float* __restrict__ l3w, const float* __restrict__ l3b,
    const float* __restrict__ l4w, const float* __restrict__ l4b,
    const float* __restrict__ l5w, const float* __restrict__ l5b,
    const int* __restrict__ hist, const int* __restrict__ bucket,
    float* __restrict__ out, int P)
{
    const int c = blockIdx.x;
    int n = hist[c];
    if (n <= 0) return;
    if (n > CAP) n = CAP;
    const int tid = threadIdx.x;
    const int g = tid >> 3;   // point slot within chunk (0..7)
    const int k = tid & 7;    // lane within point group

    __shared__ float s_emb[8][68];   // emb_x (63), stride 68 -> conflict-free b128
    __shared__ float s_l4[8][68];    // [h3(32) | emb_d(27)] = 59
    __shared__ float s_act[8][36];   // 32-wide activations, stride 36

    const float* w1 = l1w + c * 2016;
    const float* w2 = l2w + c * 1056;
    const float* w3 = l3w + c * 1024;
    const float* w4 = l4w + c * 1888;
    const float* w5 = l5w + c * 96;

    // per-block preloads (lane-owned)
    const float4 b1 = *(const float4*)(l1b + c*32 + 4*k);
    float b2v[4];
    #pragma unroll
    for (int j = 0; j < 4; ++j) b2v[j] = l2b[c*33 + 4*k + j];
    const float b2d = l2b[c*33 + 32];
    const float4 b3 = *(const float4*)(l3b + c*32 + 4*k);
    const float4 b4 = *(const float4*)(l4b + c*32 + 4*k);
    const float b50 = l5b[c*3+0], b51 = l5b[c*3+1], b52 = l5b[c*3+2];
    float w2c[4];
    #pragma unroll
    for (int j = 0; j < 4; ++j) w2c[j] = w2[(4*k+j)*33 + 32];   // density column
    float w5r[4][3];
    #pragma unroll
    for (int j = 0; j < 4; ++j)
        #pragma unroll
        for (int jj = 0; jj < 3; ++jj) w5r[j][jj] = w5[(4*k+j)*3 + jj];

    for (int base = 0; base < n; base += 8) {
        const int idx = base + g;
        const bool live = idx < n;
        const int p = bucket[c*CAP + (live ? idx : 0)];

        const float x0 = xg[p*3+0], x1 = xg[p*3+1], x2 = xg[p*3+2];
        const float d0 = dg[p*3+0], d1 = dg[p*3+1], d2 = dg[p*3+2];

        for (int m = k; m < 63; m += 8) s_emb[g][m] = emb_val(m, x0, x1, x2);
        for (int m = k; m < 27; m += 8) s_l4[g][32+m] = emb_val(m, d0, d1, d2);
        __syncthreads();

        // ---- L1: 63 -> 32, relu ----
        float a0 = b1.x, a1 = b1.y, a2 = b1.z, a3 = b1.w;
        #pragma unroll
        for (int t = 0; t < 16; ++t) {
            const float4 av = *(const float4*)&s_emb[g][4*t];
            const int jmax = (t == 15) ? 3 : 4;
            #pragma unroll
            for (int j = 0; j < jmax; ++j) {
                const float aj = (&av.x)[j];
                const float4 wv = *(const float4*)(w1 + (4*t+j)*32 + 4*k);
                a0 = fmaf(aj, wv.x, a0); a1 = fmaf(aj, wv.y, a1);
                a2 = fmaf(aj, wv.z, a2); a3 = fmaf(aj, wv.w, a3);
            }
        }
        const float h10 = fmaxf(a0,0.f), h11 = fmaxf(a1,0.f);
        const float h12 = fmaxf(a2,0.f), h13 = fmaxf(a3,0.f);

        // density = relu(h1 . w2[:,32] + b2d)
        float dp = h10*w2c[0] + h11*w2c[1] + h12*w2c[2] + h13*w2c[3];
        dp += __shfl_xor(dp, 1, 8);
        dp += __shfl_xor(dp, 2, 8);
        dp += __shfl_xor(dp, 4, 8);
        const float density = fmaxf(dp + b2d, 0.f);

        *(float4*)&s_act[g][4*k] = make_float4(h10, h11, h12, h13);
        __syncthreads();

        // ---- L2: 32 -> 32 (cols 0..31), relu ----
        a0 = b2v[0]; a1 = b2v[1]; a2 = b2v[2]; a3 = b2v[3];
        #pragma unroll
        for (int t = 0; t < 8; ++t) {
            const float4 av = *(const float4*)&s_act[g][4*t];
            #pragma unroll
            for (int j = 0; j < 4; ++j) {
                const float aj = (&av.x)[j];
                const float* wr = w2 + (4*t+j)*33 + 4*k;   // row not 16B-aligned (stride 33)
                a0 = fmaf(aj, wr[0], a0); a1 = fmaf(aj, wr[1], a1);
                a2 = fmaf(aj, wr[2], a2); a3 = fmaf(aj, wr[3], a3);
            }
        }
        const float h20 = fmaxf(a0,0.f), h21 = fmaxf(a1,0.f);
        const float h22 = fmaxf(a2,0.f), h23 = fmaxf(a3,0.f);
        __syncthreads();                      // everyone done reading h1
        *(float4*)&s_act[g][4*k] = make_float4(h20, h21, h22, h23);
        __syncthreads();

        // ---- L3: 32 -> 32, no activation ----
        a0 = b3.x; a1 = b3.y; a2 = b3.z; a3 = b3.w;
        #pragma unroll
        for (int t = 0; t < 8; ++t) {
            const float4 av = *(const float4*)&s_act[g][4*t];
            #pragma unroll
            for (int j = 0; j < 4; ++j) {
                const float aj = (&av.x)[j];
                const float4 wv = *(const float4*)(w3 + (4*t+j)*32 + 4*k);
                a0 = fmaf(aj, wv.x, a0); a1 = fmaf(aj, wv.y, a1);
                a2 = fmaf(aj, wv.z, a2); a3 = fmaf(aj, wv.w, a3);
            }
        }
        __syncthreads();                      // everyone done reading h2
        *(float4*)&s_l4[g][4*k] = make_float4(a0, a1, a2, a3);   // h3 into concat row
        __syncthreads();

        // ---- L4: 59 -> 32, relu ----
        a0 = b4.x; a1 = b4.y; a2 = b4.z; a3 = b4.w;
        #pragma unroll
        for (int t = 0; t < 15; ++t) {
            const float4 av = *(const float4*)&s_l4[g][4*t];
            const int jmax = (t == 14) ? 3 : 4;
            #pragma unroll
            for (int j = 0; j < jmax; ++j) {
                const float aj = (&av.x)[j];
                const float4 wv = *(const float4*)(w4 + (4*t+j)*32 + 4*k);
                a0 = fmaf(aj, wv.x, a0); a1 = fmaf(aj, wv.y, a1);
                a2 = fmaf(aj, wv.z, a2); a3 = fmaf(aj, wv.w, a3);
            }
        }
        const float h40 = fmaxf(a0,0.f), h41 = fmaxf(a1,0.f);
        const float h42 = fmaxf(a2,0.f), h43 = fmaxf(a3,0.f);

        // ---- L5: 32 -> 3, sigmoid ----
        float c0 = h40*w5r[0][0] + h41*w5r[1][0] + h42*w5r[2][0] + h43*w5r[3][0];
        float c1 = h40*w5r[0][1] + h41*w5r[1][1] + h42*w5r[2][1] + h43*w5r[3][1];
        float c2 = h40*w5r[0][2] + h41*w5r[1][2] + h42*w5r[2][2] + h43*w5r[3][2];
        #pragma unroll
        for (int m = 1; m <= 4; m <<= 1) {
            c0 += __shfl_xor(c0, m, 8);
            c1 += __shfl_xor(c1, m, 8);
            c2 += __shfl_xor(c2, m, 8);
        }

        if (live && k == 0) {
            out[p*3+0] = 1.0f / (1.0f + expf(-(c0 + b50)));
            out[p*3+1] = 1.0f / (1.0f + expf(-(c1 + b51)));
            out[p*3+2] = 1.0f / (1.0f + expf(-(c2 + b52)));
            out[(size_t)P*3 + p] = density;
        }
        __syncthreads();   // protect LDS before next chunk
    }
}

extern "C" void kernel_launch(void* const* d_in, const int* in_sizes, int n_in,
                              void* d_out, int out_size, void* d_ws, size_t ws_size,
                              hipStream_t stream) {
    const float* x   = (const float*)d_in[0];
    const float* d   = (const float*)d_in[1];
    const float* l1w = (const float*)d_in[2];
    const float* l1b = (const float*)d_in[3];
    const float* l2w = (const float*)d_in[4];
    const float* l2b = (const float*)d_in[5];
    const float* l3w = (const float*)d_in[6];
    const float* l3b = (const float*)d_in[7];
    const float* l4w = (const float*)d_in[8];
    const float* l4b = (const float*)d_in[9];
    const float* l5w = (const float*)d_in[10];
    const float* l5b = (const float*)d_in[11];
    float* out = (float*)d_out;

    const int P = in_sizes[0] / 3;   // 32768
    int* ws = (int*)d_ws;
    int* hist   = ws;
    int* bucket = ws + NCELL;

    k_zero<<<(NCELL + 255)/256, 256, 0, stream>>>(hist);
    k_bin<<<(P + 255)/256, 256, 0, stream>>>(x, out, hist, bucket, P);
    k_fwd<<<NCELL, 64, 0, stream>>>(x, d, l1w, l1b, l2w, l2b, l3w, l3b,
                                    l4w, l4b, l5w, l5b, hist, bucket, out, P);
}

// Round 5
// 180.518 us; speedup vs baseline: 2.4661x; 2.4661x over previous
//
#include <hip/hip_runtime.h>
#include <math.h>

#define GN 16
#define NCELL 4096

// ws layout (ints): cell[P] @0, order[P] @P, hist @2P, offs @2P+4096,
//                   cursor @2P+8192, total @2P+12288

__device__ __forceinline__ int cell_of(float x0, float x1, float x2) {
    int ix = (int)(x0 / 0.1875f + 8.0f); ix = ix < 0 ? 0 : (ix > 15 ? 15 : ix);
    int iy = (int)(x1 / 0.1875f + 8.0f); iy = iy < 0 ? 0 : (iy > 15 ? 15 : iy);
    int iz = (int)(x2 / 0.1875f + 8.0f); iz = iz < 0 ? 0 : (iz > 15 ? 15 : iz);
    return (ix * GN + iy) * GN + iz;
}

// emb layout: [v0,v1,v2, sin(2^0 v*), cos(2^0 v*), sin(2^1 v*), ...]
__device__ __forceinline__ float emb_val(int m, float v0, float v1, float v2) {
    if (m == 0) return v0;
    if (m == 1) return v1;
    if (m == 2) return v2;
    int t = m - 3, j = t / 6, rem = t - j * 6, comp = rem % 3;
    float v = (comp == 0) ? v0 : ((comp == 1) ? v1 : v2);
    float s = ldexpf(v, j);
    return (rem < 3) ? sinf(s) : cosf(s);
}

__global__ void k_zero(int* __restrict__ hist) {
    int t = blockIdx.x * blockDim.x + threadIdx.x;
    if (t < NCELL) hist[t] = 0;
}

__global__ void k_classify(const float* __restrict__ xg, float* __restrict__ out,
                           int* __restrict__ cell, int* __restrict__ hist, int P) {
    int p = blockIdx.x * blockDim.x + threadIdx.x;
    if (p >= P) return;
    float x0 = xg[p*3+0], x1 = xg[p*3+1], x2 = xg[p*3+2];
    bool mask = (fabsf(x0) < 1.5f) && (fabsf(x1) < 1.5f) && (fabsf(x2) < 1.5f);
    if (mask) {
        int c = cell_of(x0, x1, x2);
        cell[p] = c;
        atomicAdd(&hist[c], 1);
    } else {
        cell[p] = -1;
        out[p*3+0] = 0.0f; out[p*3+1] = 0.0f; out[p*3+2] = 0.0f;
        out[(size_t)P*3 + p] = 0.0f;
    }
}

__global__ __launch_bounds__(1024) void k_scan(const int* __restrict__ hist,
                                               int* __restrict__ offs,
                                               int* __restrict__ cursor,
                                               int* __restrict__ total) {
    __shared__ int s[1024];
    const int t = threadIdx.x;
    const int base = t * 4;
    int a0 = hist[base+0], a1 = hist[base+1], a2 = hist[base+2], a3 = hist[base+3];
    int sum = a0 + a1 + a2 + a3;
    s[t] = sum;
    __syncthreads();
    #pragma unroll
    for (int off = 1; off < 1024; off <<= 1) {
        int v = (t >= off) ? s[t - off] : 0;
        __syncthreads();
        s[t] += v;
        __syncthreads();
    }
    int excl = s[t] - sum;
    int e0 = excl, e1 = e0 + a0, e2 = e1 + a1, e3 = e2 + a2;
    offs[base+0] = e0; offs[base+1] = e1; offs[base+2] = e2; offs[base+3] = e3;
    cursor[base+0] = e0; cursor[base+1] = e1; cursor[base+2] = e2; cursor[base+3] = e3;
    if (t == 1023) *total = s[1023];
}

__global__ void k_scatter(const int* __restrict__ cell, int* __restrict__ cursor,
                          int* __restrict__ order, int P) {
    int p = blockIdx.x * blockDim.x + threadIdx.x;
    if (p >= P) return;
    int c = cell[p];
    if (c >= 0) {
        int pos = atomicAdd(&cursor[c], 1);
        order[pos] = p;
    }
}

// 256 threads = 32 points (8 lanes/point, lane owns outputs 4k..4k+3).
// All LDS sharing is intra-8-lane-group; b128 activation reads are
// same-address per group, bank-disjoint across groups.
__global__ __launch_bounds__(256, 4) void k_fwd(
    const float* __restrict__ xg, const float* __restrict__ dg,
    const float* __restrict__ l1w, const float* __restrict__ l1b,
    const float* __restrict__ l2w, const float* __restrict__ l2b,
    const float* __restrict__ l3w, const float* __restrict__ l3b,
    const float* __restrict__ l4w, const float* __restrict__ l4b,
    const float* __restrict__ l5w, const float* __restrict__ l5b,
    const int* __restrict__ order, const int* __restrict__ cellArr,
    const int* __restrict__ total,
    float* __restrict__ out, int P)
{
    const int n = *total;
    if ((int)blockIdx.x * 32 >= n) return;
    const int tid = threadIdx.x;
    const int g = tid >> 3;          // point slot in block (0..31)
    const int k = tid & 7;           // lane in group
    const int s = blockIdx.x * 32 + g;
    const bool live = s < n;
    const int p = order[live ? s : 0];
    const int cell = cellArr[p];

    __shared__ float s_emb[32][68];  // emb_x (63); stride 68: banks 4(g+t) mod 32
    __shared__ float s_h[32][36];    // 32-wide activations
    __shared__ float s_l4[32][68];   // [h3(32) | emb_d(27)]

    const float x0 = xg[p*3+0], x1 = xg[p*3+1], x2 = xg[p*3+2];
    const float d0 = dg[p*3+0], d1 = dg[p*3+1], d2 = dg[p*3+2];

    #pragma unroll
    for (int m = k; m < 63; m += 8) s_emb[g][m] = emb_val(m, x0, x1, x2);
    #pragma unroll
    for (int m = k; m < 27; m += 8) s_l4[g][32+m] = emb_val(m, d0, d1, d2);
    __syncthreads();

    const float* w1 = l1w + cell*2016;
    const float* w2 = l2w + cell*1056;
    const float* w3 = l3w + cell*1024;
    const float* w4 = l4w + cell*1888;
    const float* w5 = l5w + cell*96;

    // ---- L1: 63 -> 32, relu ----
    float4 bb = *(const float4*)(l1b + cell*32 + 4*k);
    float a0 = bb.x, a1 = bb.y, a2 = bb.z, a3 = bb.w;
    #pragma unroll 5
    for (int t = 0; t < 15; ++t) {               // 60 inputs in float4 tiles
        const float4 av = *(const float4*)&s_emb[g][4*t];
        #pragma unroll
        for (int j = 0; j < 4; ++j) {
            const float aj = (&av.x)[j];
            const float4 wv = *(const float4*)(w1 + (4*t+j)*32 + 4*k);
            a0 = fmaf(aj, wv.x, a0); a1 = fmaf(aj, wv.y, a1);
            a2 = fmaf(aj, wv.z, a2); a3 = fmaf(aj, wv.w, a3);
        }
    }
    #pragma unroll
    for (int u = 60; u < 63; ++u) {              // tail inputs 60..62
        const float aj = s_emb[g][u];
        const float4 wv = *(const float4*)(w1 + u*32 + 4*k);
        a0 = fmaf(aj, wv.x, a0); a1 = fmaf(aj, wv.y, a1);
        a2 = fmaf(aj, wv.z, a2); a3 = fmaf(aj, wv.w, a3);
    }
    const float h10 = fmaxf(a0,0.f), h11 = fmaxf(a1,0.f);
    const float h12 = fmaxf(a2,0.f), h13 = fmaxf(a3,0.f);

    // density = relu(h1 . w2[:,32] + b2d)
    float dp = h10*w2[(4*k+0)*33+32] + h11*w2[(4*k+1)*33+32]
             + h12*w2[(4*k+2)*33+32] + h13*w2[(4*k+3)*33+32];
    dp += __shfl_xor(dp, 1, 8);
    dp += __shfl_xor(dp, 2, 8);
    dp += __shfl_xor(dp, 4, 8);
    const float density = fmaxf(dp + l2b[cell*33+32], 0.f);

    *(float4*)&s_h[g][4*k] = make_float4(h10, h11, h12, h13);
    __syncthreads();

    // ---- L2: 32 -> 32 (cols 0..31), relu; rows stride 33 (scalar loads) ----
    a0 = l2b[cell*33 + 4*k+0]; a1 = l2b[cell*33 + 4*k+1];
    a2 = l2b[cell*33 + 4*k+2]; a3 = l2b[cell*33 + 4*k+3];
    #pragma unroll 4
    for (int t = 0; t < 8; ++t) {
        const float4 av = *(const float4*)&s_h[g][4*t];
        #pragma unroll
        for (int j = 0; j < 4; ++j) {
            const float aj = (&av.x)[j];
            const float* wr = w2 + (4*t+j)*33 + 4*k;
            a0 = fmaf(aj, wr[0], a0); a1 = fmaf(aj, wr[1], a1);
            a2 = fmaf(aj, wr[2], a2); a3 = fmaf(aj, wr[3], a3);
        }
    }
    const float h20 = fmaxf(a0,0.f), h21 = fmaxf(a1,0.f);
    const float h22 = fmaxf(a2,0.f), h23 = fmaxf(a3,0.f);
    __syncthreads();                    // all reads of s_h (h1) done
    *(float4*)&s_h[g][4*k] = make_float4(h20, h21, h22, h23);
    __syncthreads();

    // ---- L3: 32 -> 32, no activation ----
    bb = *(const float4*)(l3b + cell*32 + 4*k);
    a0 = bb.x; a1 = bb.y; a2 = bb.z; a3 = bb.w;
    #pragma unroll 4
    for (int t = 0; t < 8; ++t) {
        const float4 av = *(const float4*)&s_h[g][4*t];
        #pragma unroll
        for (int j = 0; j < 4; ++j) {
            const float aj = (&av.x)[j];
            const float4 wv = *(const float4*)(w3 + (4*t+j)*32 + 4*k);
            a0 = fmaf(aj, wv.x, a0); a1 = fmaf(aj, wv.y, a1);
            a2 = fmaf(aj, wv.z, a2); a3 = fmaf(aj, wv.w, a3);
        }
    }
    *(float4*)&s_l4[g][4*k] = make_float4(a0, a1, a2, a3);   // h3 into concat row
    __syncthreads();

    // ---- L4: [h3(32)|emb_d(27)] = 59 -> 32, relu ----
    bb = *(const float4*)(l4b + cell*32 + 4*k);
    a0 = bb.x; a1 = bb.y; a2 = bb.z; a3 = bb.w;
    #pragma unroll 7
    for (int t = 0; t < 14; ++t) {               // 56 inputs in float4 tiles
        const float4 av = *(const float4*)&s_l4[g][4*t];
        #pragma unroll
        for (int j = 0; j < 4; ++j) {
            const float aj = (&av.x)[j];
            const float4 wv = *(const float4*)(w4 + (4*t+j)*32 + 4*k);
            a0 = fmaf(aj, wv.x, a0); a1 = fmaf(aj, wv.y, a1);
            a2 = fmaf(aj, wv.z, a2); a3 = fmaf(aj, wv.w, a3);
        }
    }
    #pragma unroll
    for (int u = 56; u < 59; ++u) {              // tail inputs 56..58
        const float aj = s_l4[g][u];
        const float4 wv = *(const float4*)(w4 + u*32 + 4*k);
        a0 = fmaf(aj, wv.x, a0); a1 = fmaf(aj, wv.y, a1);
        a2 = fmaf(aj, wv.z, a2); a3 = fmaf(aj, wv.w, a3);
    }
    const float h40 = fmaxf(a0,0.f), h41 = fmaxf(a1,0.f);
    const float h42 = fmaxf(a2,0.f), h43 = fmaxf(a3,0.f);

    // ---- L5: 32 -> 3, sigmoid ----
    float c0 = h40*w5[(4*k+0)*3+0] + h41*w5[(4*k+1)*3+0]
             + h42*w5[(4*k+2)*3+0] + h43*w5[(4*k+3)*3+0];
    float c1 = h40*w5[(4*k+0)*3+1] + h41*w5[(4*k+1)*3+1]
             + h42*w5[(4*k+2)*3+1] + h43*w5[(4*k+3)*3+1];
    float c2 = h40*w5[(4*k+0)*3+2] + h41*w5[(4*k+1)*3+2]
             + h42*w5[(4*k+2)*3+2] + h43*w5[(4*k+3)*3+2];
    #pragma unroll
    for (int m = 1; m <= 4; m <<= 1) {
        c0 += __shfl_xor(c0, m, 8);
        c1 += __shfl_xor(c1, m, 8);
        c2 += __shfl_xor(c2, m, 8);
    }

    if (live && k == 0) {
        out[p*3+0] = 1.0f / (1.0f + expf(-(c0 + l5b[cell*3+0])));
        out[p*3+1] = 1.0f / (1.0f + expf(-(c1 + l5b[cell*3+1])));
        out[p*3+2] = 1.0f / (1.0f + expf(-(c2 + l5b[cell*3+2])));
        out[(size_t)P*3 + p] = density;
    }
}

extern "C" void kernel_launch(void* const* d_in, const int* in_sizes, int n_in,
                              void* d_out, int out_size, void* d_ws, size_t ws_size,
                              hipStream_t stream) {
    const float* x   = (const float*)d_in[0];
    const float* d   = (const float*)d_in[1];
    const float* l1w = (const float*)d_in[2];
    const float* l1b = (const float*)d_in[3];
    const float* l2w = (const float*)d_in[4];
    const float* l2b = (const float*)d_in[5];
    const float* l3w = (const float*)d_in[6];
    const float* l3b = (const float*)d_in[7];
    const float* l4w = (const float*)d_in[8];
    const float* l4b = (const float*)d_in[9];
    const float* l5w = (const float*)d_in[10];
    const float* l5b = (const float*)d_in[11];
    float* out = (float*)d_out;

    const int P = in_sizes[0] / 3;   // 32768
    int* ws = (int*)d_ws;
    int* cell   = ws;
    int* order  = ws + P;
    int* hist   = ws + 2*P;
    int* offs   = ws + 2*P + NCELL;
    int* cursor = ws + 2*P + 2*NCELL;
    int* total  = ws + 2*P + 3*NCELL;

    k_zero<<<(NCELL + 255)/256, 256, 0, stream>>>(hist);
    k_classify<<<(P + 255)/256, 256, 0, stream>>>(x, out, cell, hist, P);
    k_scan<<<1, 1024, 0, stream>>>(hist, offs, cursor, total);
    k_scatter<<<(P + 255)/256, 256, 0, stream>>>(cell, cursor, order, P);
    k_fwd<<<(P + 31)/32, 256, 0, stream>>>(x, d, l1w, l1b, l2w, l2b, l3w, l3b,
                                           l4w, l4b, l5w, l5b,
                                           order, cell, total, out, P);
}